// Round 18
// baseline (228.923 us; speedup 1.0000x reference)
//
#include <hip/hip_runtime.h>

#define N_NODES 50000
#define N_EDGES 300000
#define IN_CH 256
#define HID 512
#define SCAN_NBLK ((N_NODES + 255) / 256)   // 196

typedef __bf16 bf16;
typedef bf16 bf16x8 __attribute__((ext_vector_type(8)));
typedef bf16 bf16x4 __attribute__((ext_vector_type(4)));
typedef bf16 bf16x2 __attribute__((ext_vector_type(2)));
typedef float f32x4 __attribute__((ext_vector_type(4)));
typedef unsigned long long u64;

__device__ __forceinline__ void load_lds16(const void* g, void* l) {
    __builtin_amdgcn_global_load_lds(
        (const __attribute__((address_space(1))) unsigned int*)g,
        (__attribute__((address_space(3))) unsigned int*)l, 16, 0, 0);
}

// ---------- inline index-dtype detection ----------
__device__ __forceinline__ int detect64(const unsigned int* __restrict__ ei) {
    unsigned v = 0;
#pragma unroll
    for (int k = 1; k < 16; k += 2) v |= ei[k];
    return v == 0;
}

__device__ __forceinline__ int load_idx(const void* ei, int i, int is64) {
    if (is64) return (int)((const long long*)ei)[i];
    return ((const int*)ei)[i];
}

// ---------- fused prologue: histogram (latency stream) + conversions (BW stream) ----------
__global__ void prep_hist(const void* __restrict__ ei, const float* __restrict__ ew,
                          u64* __restrict__ pc,
                          const float* __restrict__ x, bf16* __restrict__ xb,
                          const float* __restrict__ W1, bf16* __restrict__ W1b, int n1,
                          const float* __restrict__ W2, bf16* __restrict__ W2b, int n2) {
    int i = blockIdx.x * blockDim.x + threadIdx.x;
    if (i < N_EDGES) {
        int is64 = detect64((const unsigned int*)ei);
        int d = load_idx(ei, N_EDGES + i, is64);
        unsigned w = (unsigned)(ew[i] * 16777216.0f);
        atomicAdd(&pc[d], (1ULL << 32) | (u64)w);
        return;
    }
    int j = i - N_EDGES;
    const int TX = N_NODES * IN_CH / 8;
    if (j < TX) {
        float4 a = ((const float4*)x)[j * 2];
        float4 b = ((const float4*)x)[j * 2 + 1];
        bf16x8 o;
        o[0] = (bf16)a.x; o[1] = (bf16)a.y; o[2] = (bf16)a.z; o[3] = (bf16)a.w;
        o[4] = (bf16)b.x; o[5] = (bf16)b.y; o[6] = (bf16)b.z; o[7] = (bf16)b.w;
        *(bf16x8*)(xb + (size_t)j * 8) = o;
    } else {
        int m = j - TX;
        if (m < n1) W1b[m] = (bf16)W1[m];
        else if (m - n1 < n2) W2b[m - n1] = (bf16)W2[m - n1];
    }
}

// ---------- scan phase A: block-local scan + dis (from packed hist) ----------
__global__ __launch_bounds__(256) void scan_partial(
    const u64* __restrict__ pc, float* __restrict__ dis,
    int* __restrict__ row_ptr, int* __restrict__ partials)
{
    __shared__ int psum[256];
    int t = threadIdx.x;
    int i = blockIdx.x * 256 + t;
    int c = 0;
    if (i < N_NODES) {
        u64 v = pc[i];
        c = (int)(v >> 32);
        float dg = 1.0f + (float)(unsigned)(v & 0xffffffffu) * (1.0f / 16777216.0f);
        dis[i] = rsqrtf(dg);
    }
    psum[t] = c;
    __syncthreads();
#pragma unroll
    for (int off = 1; off < 256; off <<= 1) {
        int v = (t >= off) ? psum[t - off] : 0;
        __syncthreads();
        psum[t] += v;
        __syncthreads();
    }
    if (i < N_NODES) row_ptr[i] = psum[t] - c;
    if (t == 255) partials[blockIdx.x] = psum[255];
}

// ---------- scan phase B+C merged ----------
__global__ __launch_bounds__(256) void scan_finish(int* __restrict__ row_ptr,
                                                   const int* __restrict__ partials) {
    __shared__ int red[4];
    __shared__ int pref;
    int b = blockIdx.x;
    int t = threadIdx.x;
    int lane = t & 63, wid = t >> 6;
    int v = (t < b) ? partials[t] : 0;
#pragma unroll
    for (int off = 32; off; off >>= 1) v += __shfl_down(v, off, 64);
    if (lane == 0) red[wid] = v;
    __syncthreads();
    if (t == 0) pref = red[0] + red[1] + red[2] + red[3];
    __syncthreads();
    int i = b * 256 + t;
    if (i < N_NODES) row_ptr[i] += pref;
    if (b == 0 && t == 0) row_ptr[N_NODES] = N_EDGES;
}

// ---------- fill CSR with PACKED edges: int2{src, coef_bits} ----------
__global__ void fill_csr(const void* __restrict__ ei, const float* __restrict__ ew,
                         const float* __restrict__ dis, const int* __restrict__ row_ptr,
                         int* __restrict__ cursor, int2* __restrict__ edges) {
    int e = blockIdx.x * blockDim.x + threadIdx.x;
    if (e >= N_EDGES) return;
    int is64 = detect64((const unsigned int*)ei);
    int s = load_idx(ei, e, is64);
    int d = load_idx(ei, N_EDGES + e, is64);
    float coef = dis[s] * ew[e] * dis[d];
    int pos = row_ptr[d] + atomicAdd(&cursor[d], 1);
    edges[pos] = make_int2(s, __float_as_int(coef));
}

// ---------- gather aggregation, C=256, 128-ch windows:
// wave = 2 nodes x 128 ch (bf16x2/lane). Block: 4 waves = 2 node-pairs. ----------
__global__ __launch_bounds__(256) void gather_agg_c256(
    const bf16* __restrict__ xb, const float* __restrict__ dis,
    const int* __restrict__ row_ptr, const int2* __restrict__ edges,
    bf16* __restrict__ agg)
{
    int wid = threadIdx.x >> 6;           // 0..3
    int lane = threadIdx.x & 63;
    int pair = wid >> 1;                  // 0..1
    int half = wid & 1;                   // 0..1 -> channel half
    int n0 = blockIdx.x * 4 + pair * 2;
    if (n0 >= N_NODES) return;
    int n1 = (n0 + 1 < N_NODES) ? n0 + 1 : n0;
    int cho = half * 128 + lane * 2;      // 128-ch window, 4B/lane

    float s0 = dis[n0]; s0 *= s0;
    float s1 = dis[n1]; s1 *= s1;
    bf16x2 t0 = *(const bf16x2*)(xb + (size_t)n0 * IN_CH + cho);
    bf16x2 t1 = *(const bf16x2*)(xb + (size_t)n1 * IN_CH + cho);
    float a0[2], a1[2];
#pragma unroll
    for (int i = 0; i < 2; ++i) { a0[i] = s0 * (float)t0[i]; a1[i] = s1 * (float)t1[i]; }

    int b0 = row_ptr[n0], c0 = row_ptr[n0 + 1] - b0;
    int b1 = row_ptr[n1], c1 = row_ptr[n1 + 1] - b1;
    int cmin = c0 < c1 ? c0 : c1;
    int k = 0;
#pragma unroll 2
    for (; k < cmin; ++k) {                       // 2 independent chains
        int2 ea = edges[b0 + k], eb = edges[b1 + k];
        float ca = __int_as_float(ea.y), cb = __int_as_float(eb.y);
        bf16x2 ra = *(const bf16x2*)(xb + (size_t)ea.x * IN_CH + cho);
        bf16x2 rb = *(const bf16x2*)(xb + (size_t)eb.x * IN_CH + cho);
#pragma unroll
        for (int i = 0; i < 2; ++i) { a0[i] += ca * (float)ra[i]; a1[i] += cb * (float)rb[i]; }
    }
    for (; k < c0; ++k) {
        int2 ea = edges[b0 + k];
        float ca = __int_as_float(ea.y);
        bf16x2 ra = *(const bf16x2*)(xb + (size_t)ea.x * IN_CH + cho);
#pragma unroll
        for (int i = 0; i < 2; ++i) a0[i] += ca * (float)ra[i];
    }
    for (; k < c1; ++k) {
        int2 eb = edges[b1 + k];
        float cb = __int_as_float(eb.y);
        bf16x2 rb = *(const bf16x2*)(xb + (size_t)eb.x * IN_CH + cho);
#pragma unroll
        for (int i = 0; i < 2; ++i) a1[i] += cb * (float)rb[i];
    }
    bf16x2 o0, o1;
#pragma unroll
    for (int i = 0; i < 2; ++i) { o0[i] = (bf16)a0[i]; o1[i] = (bf16)a1[i]; }
    *(bf16x2*)(agg + (size_t)n0 * IN_CH + cho) = o0;
    *(bf16x2*)(agg + (size_t)n1 * IN_CH + cho) = o1;
}

// ---------- gather aggregation, C=512, 128-ch windows:
// wave = 2 nodes x 128 ch (bf16x2/lane). Block: 4 waves = 1 node-pair x 4 windows. ----------
__global__ __launch_bounds__(256) void gather_agg_c512(
    const bf16* __restrict__ p, const float* __restrict__ dis,
    const int* __restrict__ row_ptr, const int2* __restrict__ edges,
    bf16* __restrict__ agg)
{
    int wid = threadIdx.x >> 6;           // 0..3 -> channel quarter
    int lane = threadIdx.x & 63;
    int n0 = blockIdx.x * 2;
    if (n0 >= N_NODES) return;
    int n1 = (n0 + 1 < N_NODES) ? n0 + 1 : n0;
    int cho = wid * 128 + lane * 2;       // 128-ch window, 4B/lane

    float s0 = dis[n0]; s0 *= s0;
    float s1 = dis[n1]; s1 *= s1;
    bf16x2 t0 = *(const bf16x2*)(p + (size_t)n0 * HID + cho);
    bf16x2 t1 = *(const bf16x2*)(p + (size_t)n1 * HID + cho);
    float a0[2], a1[2];
#pragma unroll
    for (int i = 0; i < 2; ++i) { a0[i] = s0 * (float)t0[i]; a1[i] = s1 * (float)t1[i]; }

    int b0 = row_ptr[n0], c0 = row_ptr[n0 + 1] - b0;
    int b1 = row_ptr[n1], c1 = row_ptr[n1 + 1] - b1;
    int cmin = c0 < c1 ? c0 : c1;
    int k = 0;
#pragma unroll 2
    for (; k < cmin; ++k) {                       // 2 independent chains
        int2 ea = edges[b0 + k], eb = edges[b1 + k];
        float ca = __int_as_float(ea.y), cb = __int_as_float(eb.y);
        bf16x2 ra = *(const bf16x2*)(p + (size_t)ea.x * HID + cho);
        bf16x2 rb = *(const bf16x2*)(p + (size_t)eb.x * HID + cho);
#pragma unroll
        for (int i = 0; i < 2; ++i) { a0[i] += ca * (float)ra[i]; a1[i] += cb * (float)rb[i]; }
    }
    for (; k < c0; ++k) {
        int2 ea = edges[b0 + k];
        float ca = __int_as_float(ea.y);
        bf16x2 ra = *(const bf16x2*)(p + (size_t)ea.x * HID + cho);
#pragma unroll
        for (int i = 0; i < 2; ++i) a0[i] += ca * (float)ra[i];
    }
    for (; k < c1; ++k) {
        int2 eb = edges[b1 + k];
        float cb = __int_as_float(eb.y);
        bf16x2 rb = *(const bf16x2*)(p + (size_t)eb.x * HID + cho);
#pragma unroll
        for (int i = 0; i < 2; ++i) a1[i] += cb * (float)rb[i];
    }
    bf16x2 o0, o1;
#pragma unroll
    for (int i = 0; i < 2; ++i) { o0[i] = (bf16)a0[i]; o1[i] = (bf16)a1[i]; }
    *(bf16x2*)(agg + (size_t)n0 * HID + cho) = o0;
    *(bf16x2*)(agg + (size_t)n1 * HID + cho) = o1;
}

// ---------- MFMA bf16 GEMM (R12/R14 measured-best): 256x128 tile, 8 waves,
// BK=32 dbuf with counted vmcnt(3), two barriers per K-tile, T1 XCD swizzle ----------
template <int K, bool PRELU, bool OUT_BF16>
__global__ __launch_bounds__(512) void gemm_mfma(
    const bf16* __restrict__ X, const bf16* __restrict__ Wt,
    const float* __restrict__ bias, const float* __restrict__ prelu_a,
    void* __restrict__ outv, int n)
{
    constexpr int T = K / 32;
    __shared__ __align__(16) bf16 As[2][256 * 32];
    __shared__ __align__(16) bf16 Bs[2][128 * 32];
    const int tid = threadIdx.x;
    const int lane = tid & 63;
    const int wid = tid >> 6;
    const int wr = wid >> 1;
    const int wc = wid & 1;

    const int nwg = gridDim.x;
    const int q = nwg >> 3, r8 = nwg & 7;
    int xcd = blockIdx.x & 7, slot = blockIdx.x >> 3;
    int newid = (xcd < r8 ? xcd * (q + 1) : r8 * (q + 1) + (xcd - r8) * q) + slot;
    const int row0 = (newid >> 2) * 256;
    const int col0 = (newid & 3) * 128;

    auto STAGE = [&](int buf, int t) {
#pragma unroll
        for (int h = 0; h < 2; ++h) {
            int ss = tid + h * 512;
            int r = ss >> 2;
            int c = (ss & 3) ^ (r & 3);
            int ra = row0 + r; if (ra >= n) ra = n - 1;
            load_lds16(X + (size_t)ra * K + t * 32 + c * 8, &As[buf][ss * 8]);
        }
        {
            int r = tid >> 2;
            int c = (tid & 3) ^ (r & 3);
            load_lds16(Wt + (size_t)(col0 + r) * K + t * 32 + c * 8, &Bs[buf][tid * 8]);
        }
    };

    f32x4 acc[4][4] = {};
    STAGE(0, 0);

#pragma unroll
    for (int t = 0; t < T; ++t) {
        if (t + 1 < T) {
            STAGE((t + 1) & 1, t + 1);
            asm volatile("s_waitcnt vmcnt(3)");
        } else {
            asm volatile("s_waitcnt vmcnt(0)");
        }
        __builtin_amdgcn_s_barrier();
        __builtin_amdgcn_sched_barrier(0);

        const bf16* Ab = As[t & 1];
        const bf16* Bb = Bs[t & 1];
        bf16x8 af[4], bfr[4];
#pragma unroll
        for (int m = 0; m < 4; ++m) {
            int r = wr * 64 + m * 16 + (lane & 15);
            int seg = r * 4 + ((lane >> 4) ^ (r & 3));
            af[m] = *(const bf16x8*)&Ab[seg * 8];
        }
#pragma unroll
        for (int nn = 0; nn < 4; ++nn) {
            int r = wc * 64 + nn * 16 + (lane & 15);
            int seg = r * 4 + ((lane >> 4) ^ (r & 3));
            bfr[nn] = *(const bf16x8*)&Bb[seg * 8];
        }
#pragma unroll
        for (int m = 0; m < 4; ++m)
#pragma unroll
            for (int nn = 0; nn < 4; ++nn)
                acc[m][nn] = __builtin_amdgcn_mfma_f32_16x16x32_bf16(
                    af[m], bfr[nn], acc[m][nn], 0, 0, 0);

        __builtin_amdgcn_sched_barrier(0);
        __builtin_amdgcn_s_barrier();
    }

    const float ap = PRELU ? *prelu_a : 0.f;
#pragma unroll
    for (int m = 0; m < 4; ++m) {
        int gr_base = row0 + wr * 64 + m * 16 + (lane >> 4) * 4;
#pragma unroll
        for (int nn = 0; nn < 4; ++nn) {
            int gc = col0 + wc * 64 + nn * 16 + (lane & 15);
            float bv = bias[gc];
#pragma unroll
            for (int j = 0; j < 4; ++j) {
                int gr = gr_base + j;
                if (gr < n) {
                    float v = acc[m][nn][j] + bv;
                    if (PRELU) v = (v >= 0.f) ? v : ap * v;
                    if (OUT_BF16) ((bf16*)outv)[(size_t)gr * HID + gc] = (bf16)v;
                    else         ((float*)outv)[(size_t)gr * HID + gc] = v;
                }
            }
        }
    }
}

extern "C" void kernel_launch(void* const* d_in, const int* in_sizes, int n_in,
                              void* d_out, int out_size, void* d_ws, size_t ws_size,
                              hipStream_t stream) {
    const float* x  = (const float*)d_in[0];
    const void*  ei = d_in[1];
    const float* ew = (const float*)d_in[2];
    const float* W1 = (const float*)d_in[3];
    const float* b1 = (const float*)d_in[4];
    const float* W2 = (const float*)d_in[5];
    const float* b2 = (const float*)d_in[6];
    const float* pa = (const float*)d_in[7];

    char* base = (char*)d_ws;
    bf16*  aggb     = (bf16*)base;                          // 51.2 MB
    bf16*  xb       = (bf16*)(base + (size_t)N_NODES * HID * 2);   // 25.6 MB
    bf16*  W1b      = xb + (size_t)N_NODES * IN_CH;
    bf16*  W2b      = W1b + HID * IN_CH;
    u64*   pc       = (u64*)(W2b + HID * HID);              // packed {count, fixpt wdeg}
    int*   cursor   = (int*)(pc + N_NODES);                 // adjacent -> one memset
    float* dis      = (float*)(cursor + N_NODES);
    int*   row_ptr  = (int*)(dis + N_NODES);                // N_NODES+1
    int2*  edges    = (int2*)(row_ptr + N_NODES + 2);       // N_EDGES (8B each), aligned
    int*   partials = (int*)(edges + N_EDGES);              // SCAN_NBLK

    bf16* p_bf = (bf16*)d_out;   // layer-1 bf16 output lives in d_out, consumed before GEMM2 writes f32

    const int NB = SCAN_NBLK;
    const int EB = (N_EDGES + 255) / 256;
    const int GEMM_NWG = (HID / 128) * ((N_NODES + 255) / 256);   // 784

    // ----- zero pc+cursor (adjacent), then fused histogram + conversions -----
    hipMemsetAsync(pc, 0, (size_t)N_NODES * (sizeof(u64) + sizeof(int)), stream);
    {
        int total = N_EDGES + N_NODES * IN_CH / 8 + HID * IN_CH + HID * HID;
        prep_hist<<<(total + 255) / 256, 256, 0, stream>>>(
            ei, ew, pc, x, xb, W1, W1b, HID * IN_CH, W2, W2b, HID * HID);
    }

    // ----- CSR build (once, reused by both layers) -----
    scan_partial<<<NB, 256, 0, stream>>>(pc, dis, row_ptr, partials);
    scan_finish<<<NB, 256, 0, stream>>>(row_ptr, partials);
    fill_csr<<<EB, 256, 0, stream>>>(ei, ew, dis, row_ptr, cursor, edges);

    // ----- layer 1: gather bf16 x (128-ch windows) -> GEMM + bias + PReLU -> bf16 p -----
    gather_agg_c256<<<(N_NODES + 3) / 4, 256, 0, stream>>>(xb, dis, row_ptr, edges, aggb);
    gemm_mfma<IN_CH, true, true><<<GEMM_NWG, 512, 0, stream>>>(
        aggb, W1b, b1, pa, p_bf, N_NODES);

    // ----- layer 2: gather bf16 p (128-ch windows, 4 waves/pair) -> GEMM + bias -> f32 -----
    gather_agg_c512<<<(N_NODES + 1) / 2, 256, 0, stream>>>(p_bf, dis, row_ptr, edges, aggb);
    gemm_mfma<HID, false, false><<<GEMM_NWG, 512, 0, stream>>>(
        aggb, W2b, b2, pa, (float*)d_out, N_NODES);
}

// Round 19
// 217.682 us; speedup vs baseline: 1.0516x; 1.0516x over previous
//
#include <hip/hip_runtime.h>

#define N_NODES 50000
#define N_EDGES 300000
#define IN_CH 256
#define HID 512
#define SCAN_NBLK ((N_NODES + 255) / 256)   // 196

typedef __bf16 bf16;
typedef bf16 bf16x8 __attribute__((ext_vector_type(8)));
typedef bf16 bf16x4 __attribute__((ext_vector_type(4)));
typedef float f32x4 __attribute__((ext_vector_type(4)));
typedef unsigned long long u64;

__device__ __forceinline__ void load_lds16(const void* g, void* l) {
    __builtin_amdgcn_global_load_lds(
        (const __attribute__((address_space(1))) unsigned int*)g,
        (__attribute__((address_space(3))) unsigned int*)l, 16, 0, 0);
}

// ---------- inline index-dtype detection ----------
__device__ __forceinline__ int detect64(const unsigned int* __restrict__ ei) {
    unsigned v = 0;
#pragma unroll
    for (int k = 1; k < 16; k += 2) v |= ei[k];
    return v == 0;
}

__device__ __forceinline__ int load_idx(const void* ei, int i, int is64) {
    if (is64) return (int)((const long long*)ei)[i];
    return ((const int*)ei)[i];
}

// ---------- fused prologue: histogram (latency stream) + conversions (BW stream) ----------
__global__ void prep_hist(const void* __restrict__ ei, const float* __restrict__ ew,
                          u64* __restrict__ pc,
                          const float* __restrict__ x, bf16* __restrict__ xb,
                          const float* __restrict__ W1, bf16* __restrict__ W1b, int n1,
                          const float* __restrict__ W2, bf16* __restrict__ W2b, int n2) {
    int i = blockIdx.x * blockDim.x + threadIdx.x;
    if (i < N_EDGES) {
        int is64 = detect64((const unsigned int*)ei);
        int d = load_idx(ei, N_EDGES + i, is64);
        unsigned w = (unsigned)(ew[i] * 16777216.0f);
        atomicAdd(&pc[d], (1ULL << 32) | (u64)w);
        return;
    }
    int j = i - N_EDGES;
    const int TX = N_NODES * IN_CH / 8;
    if (j < TX) {
        float4 a = ((const float4*)x)[j * 2];
        float4 b = ((const float4*)x)[j * 2 + 1];
        bf16x8 o;
        o[0] = (bf16)a.x; o[1] = (bf16)a.y; o[2] = (bf16)a.z; o[3] = (bf16)a.w;
        o[4] = (bf16)b.x; o[5] = (bf16)b.y; o[6] = (bf16)b.z; o[7] = (bf16)b.w;
        *(bf16x8*)(xb + (size_t)j * 8) = o;
    } else {
        int m = j - TX;
        if (m < n1) W1b[m] = (bf16)W1[m];
        else if (m - n1 < n2) W2b[m - n1] = (bf16)W2[m - n1];
    }
}

// ---------- scan phase A: block-local scan + dis (from packed hist) ----------
__global__ __launch_bounds__(256) void scan_partial(
    const u64* __restrict__ pc, float* __restrict__ dis,
    int* __restrict__ row_ptr, int* __restrict__ partials)
{
    __shared__ int psum[256];
    int t = threadIdx.x;
    int i = blockIdx.x * 256 + t;
    int c = 0;
    if (i < N_NODES) {
        u64 v = pc[i];
        c = (int)(v >> 32);
        float dg = 1.0f + (float)(unsigned)(v & 0xffffffffu) * (1.0f / 16777216.0f);
        dis[i] = rsqrtf(dg);
    }
    psum[t] = c;
    __syncthreads();
#pragma unroll
    for (int off = 1; off < 256; off <<= 1) {
        int v = (t >= off) ? psum[t - off] : 0;
        __syncthreads();
        psum[t] += v;
        __syncthreads();
    }
    if (i < N_NODES) row_ptr[i] = psum[t] - c;
    if (t == 255) partials[blockIdx.x] = psum[255];
}

// ---------- scan phase B+C merged ----------
__global__ __launch_bounds__(256) void scan_finish(int* __restrict__ row_ptr,
                                                   const int* __restrict__ partials) {
    __shared__ int red[4];
    __shared__ int pref;
    int b = blockIdx.x;
    int t = threadIdx.x;
    int lane = t & 63, wid = t >> 6;
    int v = (t < b) ? partials[t] : 0;
#pragma unroll
    for (int off = 32; off; off >>= 1) v += __shfl_down(v, off, 64);
    if (lane == 0) red[wid] = v;
    __syncthreads();
    if (t == 0) pref = red[0] + red[1] + red[2] + red[3];
    __syncthreads();
    int i = b * 256 + t;
    if (i < N_NODES) row_ptr[i] += pref;
    if (b == 0 && t == 0) row_ptr[N_NODES] = N_EDGES;
}

// ---------- fill CSR with PACKED edges: int2{src, coef_bits} ----------
__global__ void fill_csr(const void* __restrict__ ei, const float* __restrict__ ew,
                         const float* __restrict__ dis, const int* __restrict__ row_ptr,
                         int* __restrict__ cursor, int2* __restrict__ edges) {
    int e = blockIdx.x * blockDim.x + threadIdx.x;
    if (e >= N_EDGES) return;
    int is64 = detect64((const unsigned int*)ei);
    int s = load_idx(ei, e, is64);
    int d = load_idx(ei, N_EDGES + e, is64);
    float coef = dis[s] * ew[e] * dis[d];
    int pos = row_ptr[d] + atomicAdd(&cursor[d], 1);
    edges[pos] = make_int2(s, __float_as_int(coef));
}

// ---------- gather C=256: ONE node per wave, self-split dual chains ----------
// Chain A = edges[beg, beg+c/2), chain B = edges[beg+c/2, end). Tail <= 1 edge.
__global__ __launch_bounds__(256) void gather_agg_c256(
    const bf16* __restrict__ xb, const float* __restrict__ dis,
    const int* __restrict__ row_ptr, const int2* __restrict__ edges,
    bf16* __restrict__ agg)
{
    int wid = threadIdx.x >> 6;
    int lane = threadIdx.x & 63;
    int node = blockIdx.x * 4 + wid;
    if (node >= N_NODES) return;

    float s = dis[node]; s *= s;
    bf16x4 t0 = *(const bf16x4*)(xb + (size_t)node * IN_CH + lane * 4);
    float a0[4], a1[4];
#pragma unroll
    for (int i = 0; i < 4; ++i) { a0[i] = s * (float)t0[i]; a1[i] = 0.f; }

    int beg = row_ptr[node], c = row_ptr[node + 1] - beg;
    int h = c >> 1;
    int bA = beg, bB = beg + h;
    int k = 0;
#pragma unroll 2
    for (; k < h; ++k) {                          // 2 chains from the same list
        int2 ea = edges[bA + k], eb = edges[bB + k];
        float ca = __int_as_float(ea.y), cb = __int_as_float(eb.y);
        bf16x4 ra = *(const bf16x4*)(xb + (size_t)ea.x * IN_CH + lane * 4);
        bf16x4 rb = *(const bf16x4*)(xb + (size_t)eb.x * IN_CH + lane * 4);
#pragma unroll
        for (int i = 0; i < 4; ++i) { a0[i] += ca * (float)ra[i]; a1[i] += cb * (float)rb[i]; }
    }
    if (c & 1) {                                  // at most one tail edge
        int2 eb = edges[bB + h];
        float cb = __int_as_float(eb.y);
        bf16x4 rb = *(const bf16x4*)(xb + (size_t)eb.x * IN_CH + lane * 4);
#pragma unroll
        for (int i = 0; i < 4; ++i) a1[i] += cb * (float)rb[i];
    }
    bf16x4 o;
#pragma unroll
    for (int i = 0; i < 4; ++i) o[i] = (bf16)(a0[i] + a1[i]);
    *(bf16x4*)(agg + (size_t)node * IN_CH + lane * 4) = o;
}

// ---------- gather C=512: ONE node x 256-ch half per wave, self-split chains ----------
__global__ __launch_bounds__(256) void gather_agg_c512(
    const bf16* __restrict__ p, const float* __restrict__ dis,
    const int* __restrict__ row_ptr, const int2* __restrict__ edges,
    bf16* __restrict__ agg)
{
    int wid = threadIdx.x >> 6;           // 0..3
    int lane = threadIdx.x & 63;
    int node = blockIdx.x * 2 + (wid >> 1);
    if (node >= N_NODES) return;
    int half = wid & 1;
    int cho = half * 256 + lane * 4;      // 256-ch window, 8B/lane

    float s = dis[node]; s *= s;
    bf16x4 t0 = *(const bf16x4*)(p + (size_t)node * HID + cho);
    float a0[4], a1[4];
#pragma unroll
    for (int i = 0; i < 4; ++i) { a0[i] = s * (float)t0[i]; a1[i] = 0.f; }

    int beg = row_ptr[node], c = row_ptr[node + 1] - beg;
    int h = c >> 1;
    int bA = beg, bB = beg + h;
    int k = 0;
#pragma unroll 2
    for (; k < h; ++k) {                          // 2 chains from the same list
        int2 ea = edges[bA + k], eb = edges[bB + k];
        float ca = __int_as_float(ea.y), cb = __int_as_float(eb.y);
        bf16x4 ra = *(const bf16x4*)(p + (size_t)ea.x * HID + cho);
        bf16x4 rb = *(const bf16x4*)(p + (size_t)eb.x * HID + cho);
#pragma unroll
        for (int i = 0; i < 4; ++i) { a0[i] += ca * (float)ra[i]; a1[i] += cb * (float)rb[i]; }
    }
    if (c & 1) {                                  // at most one tail edge
        int2 eb = edges[bB + h];
        float cb = __int_as_float(eb.y);
        bf16x4 rb = *(const bf16x4*)(p + (size_t)eb.x * HID + cho);
#pragma unroll
        for (int i = 0; i < 4; ++i) a1[i] += cb * (float)rb[i];
    }
    bf16x4 o;
#pragma unroll
    for (int i = 0; i < 4; ++i) o[i] = (bf16)(a0[i] + a1[i]);
    *(bf16x4*)(agg + (size_t)node * HID + cho) = o;
}

// ---------- MFMA bf16 GEMM (R12/R14 measured-best): 256x128 tile, 8 waves,
// BK=32 dbuf with counted vmcnt(3), two barriers per K-tile, T1 XCD swizzle ----------
template <int K, bool PRELU, bool OUT_BF16>
__global__ __launch_bounds__(512) void gemm_mfma(
    const bf16* __restrict__ X, const bf16* __restrict__ Wt,
    const float* __restrict__ bias, const float* __restrict__ prelu_a,
    void* __restrict__ outv, int n)
{
    constexpr int T = K / 32;
    __shared__ __align__(16) bf16 As[2][256 * 32];
    __shared__ __align__(16) bf16 Bs[2][128 * 32];
    const int tid = threadIdx.x;
    const int lane = tid & 63;
    const int wid = tid >> 6;
    const int wr = wid >> 1;
    const int wc = wid & 1;

    const int nwg = gridDim.x;
    const int q = nwg >> 3, r8 = nwg & 7;
    int xcd = blockIdx.x & 7, slot = blockIdx.x >> 3;
    int newid = (xcd < r8 ? xcd * (q + 1) : r8 * (q + 1) + (xcd - r8) * q) + slot;
    const int row0 = (newid >> 2) * 256;
    const int col0 = (newid & 3) * 128;

    auto STAGE = [&](int buf, int t) {
#pragma unroll
        for (int h = 0; h < 2; ++h) {
            int ss = tid + h * 512;
            int r = ss >> 2;
            int c = (ss & 3) ^ (r & 3);
            int ra = row0 + r; if (ra >= n) ra = n - 1;
            load_lds16(X + (size_t)ra * K + t * 32 + c * 8, &As[buf][ss * 8]);
        }
        {
            int r = tid >> 2;
            int c = (tid & 3) ^ (r & 3);
            load_lds16(Wt + (size_t)(col0 + r) * K + t * 32 + c * 8, &Bs[buf][tid * 8]);
        }
    };

    f32x4 acc[4][4] = {};
    STAGE(0, 0);

#pragma unroll
    for (int t = 0; t < T; ++t) {
        if (t + 1 < T) {
            STAGE((t + 1) & 1, t + 1);
            asm volatile("s_waitcnt vmcnt(3)");
        } else {
            asm volatile("s_waitcnt vmcnt(0)");
        }
        __builtin_amdgcn_s_barrier();
        __builtin_amdgcn_sched_barrier(0);

        const bf16* Ab = As[t & 1];
        const bf16* Bb = Bs[t & 1];
        bf16x8 af[4], bfr[4];
#pragma unroll
        for (int m = 0; m < 4; ++m) {
            int r = wr * 64 + m * 16 + (lane & 15);
            int seg = r * 4 + ((lane >> 4) ^ (r & 3));
            af[m] = *(const bf16x8*)&Ab[seg * 8];
        }
#pragma unroll
        for (int nn = 0; nn < 4; ++nn) {
            int r = wc * 64 + nn * 16 + (lane & 15);
            int seg = r * 4 + ((lane >> 4) ^ (r & 3));
            bfr[nn] = *(const bf16x8*)&Bb[seg * 8];
        }
#pragma unroll
        for (int m = 0; m < 4; ++m)
#pragma unroll
            for (int nn = 0; nn < 4; ++nn)
                acc[m][nn] = __builtin_amdgcn_mfma_f32_16x16x32_bf16(
                    af[m], bfr[nn], acc[m][nn], 0, 0, 0);

        __builtin_amdgcn_sched_barrier(0);
        __builtin_amdgcn_s_barrier();
    }

    const float ap = PRELU ? *prelu_a : 0.f;
#pragma unroll
    for (int m = 0; m < 4; ++m) {
        int gr_base = row0 + wr * 64 + m * 16 + (lane >> 4) * 4;
#pragma unroll
        for (int nn = 0; nn < 4; ++nn) {
            int gc = col0 + wc * 64 + nn * 16 + (lane & 15);
            float bv = bias[gc];
#pragma unroll
            for (int j = 0; j < 4; ++j) {
                int gr = gr_base + j;
                if (gr < n) {
                    float v = acc[m][nn][j] + bv;
                    if (PRELU) v = (v >= 0.f) ? v : ap * v;
                    if (OUT_BF16) ((bf16*)outv)[(size_t)gr * HID + gc] = (bf16)v;
                    else         ((float*)outv)[(size_t)gr * HID + gc] = v;
                }
            }
        }
    }
}

extern "C" void kernel_launch(void* const* d_in, const int* in_sizes, int n_in,
                              void* d_out, int out_size, void* d_ws, size_t ws_size,
                              hipStream_t stream) {
    const float* x  = (const float*)d_in[0];
    const void*  ei = d_in[1];
    const float* ew = (const float*)d_in[2];
    const float* W1 = (const float*)d_in[3];
    const float* b1 = (const float*)d_in[4];
    const float* W2 = (const float*)d_in[5];
    const float* b2 = (const float*)d_in[6];
    const float* pa = (const float*)d_in[7];

    char* base = (char*)d_ws;
    bf16*  aggb     = (bf16*)base;                          // 51.2 MB
    bf16*  xb       = (bf16*)(base + (size_t)N_NODES * HID * 2);   // 25.6 MB
    bf16*  W1b      = xb + (size_t)N_NODES * IN_CH;
    bf16*  W2b      = W1b + HID * IN_CH;
    u64*   pc       = (u64*)(W2b + HID * HID);              // packed {count, fixpt wdeg}
    int*   cursor   = (int*)(pc + N_NODES);                 // adjacent -> one memset
    float* dis      = (float*)(cursor + N_NODES);
    int*   row_ptr  = (int*)(dis + N_NODES);                // N_NODES+1
    int2*  edges    = (int2*)(row_ptr + N_NODES + 2);       // N_EDGES (8B each), aligned
    int*   partials = (int*)(edges + N_EDGES);              // SCAN_NBLK

    bf16* p_bf = (bf16*)d_out;   // layer-1 bf16 output lives in d_out, consumed before GEMM2 writes f32

    const int NB = SCAN_NBLK;
    const int EB = (N_EDGES + 255) / 256;
    const int GEMM_NWG = (HID / 128) * ((N_NODES + 255) / 256);   // 784

    // ----- zero pc+cursor (adjacent), then fused histogram + conversions -----
    hipMemsetAsync(pc, 0, (size_t)N_NODES * (sizeof(u64) + sizeof(int)), stream);
    {
        int total = N_EDGES + N_NODES * IN_CH / 8 + HID * IN_CH + HID * HID;
        prep_hist<<<(total + 255) / 256, 256, 0, stream>>>(
            ei, ew, pc, x, xb, W1, W1b, HID * IN_CH, W2, W2b, HID * HID);
    }

    // ----- CSR build (once, reused by both layers) -----
    scan_partial<<<NB, 256, 0, stream>>>(pc, dis, row_ptr, partials);
    scan_finish<<<NB, 256, 0, stream>>>(row_ptr, partials);
    fill_csr<<<EB, 256, 0, stream>>>(ei, ew, dis, row_ptr, cursor, edges);

    // ----- layer 1: gather bf16 x -> GEMM + bias + PReLU -> bf16 p (in d_out) -----
    gather_agg_c256<<<(N_NODES + 3) / 4, 256, 0, stream>>>(xb, dis, row_ptr, edges, aggb);
    gemm_mfma<IN_CH, true, true><<<GEMM_NWG, 512, 0, stream>>>(
        aggb, W1b, b1, pa, p_bf, N_NODES);

    // ----- layer 2: gather bf16 p (1 node x 256-ch half per wave) -> GEMM + bias -> f32 -----
    gather_agg_c512<<<(N_NODES + 1) / 2, 256, 0, stream>>>(p_bf, dis, row_ptr, edges, aggb);
    gemm_mfma<HID, false, false><<<GEMM_NWG, 512, 0, stream>>>(
        aggb, W2b, b2, pa, (float*)d_out, N_NODES);
}